// Round 6
// baseline (245.584 us; speedup 1.0000x reference)
//
#include <hip/hip_runtime.h>
#include <hip/hip_bf16.h>

// ContrastiveLoss: loss = mean_i [ logsumexp_j(logits[i,:]) - pos_sim[i,i] ]
// logits = [20*xn@tn^T | 20*xn@hn^T + I], rows normalized.
// Round 14: keep R13's winning TLP structure (4 blocks/CU, 44.4us gemm,
// prediction matched); fix the two counter-visible leaks:
//  1) FETCH_SIZE doubled to 39MB under R13's 1D XCD swizzle (working set
//     full-A 4MB + B 1MB > 4MB L2 -> thrash). New 2D partition: each XCD
//     owns a 16x16-tile region (A 2MB + B 2MB; ~3MB concurrent) -> L2-fits.
//  2) finalize fused into gemm (device-scope done-counter, last block
//     reduces): 3 launches -> 2. Probes whether the constant ~85us
//     non-gemm gap is per-launch overhead (gap shrinks) or fixed (doesn't).
//  - R8-R12 lesson kept: intra-block schedules (dbuf/counted-vmcnt/fine
//    phases) are NULL at 1-2 blocks/CU; TLP is the lever (m114).
//  - Proven pieces untouched: 0-conflict XOR-swizzled 16B-chunk staging,
//    i8 16x16x64 MFMA frag math, epilogue map, register diet (64V+64A).
//  - scaled-MFMA banned (R2/R4); b64 LDS reads banned (R5); setprio off
//    (m190: negative on lockstep GEMM).
//  - logit = acc * (20/127^2); diag cancellation keeps i8 loss error ~1e-3.

#define AS1 __attribute__((address_space(1)))
#define AS3 __attribute__((address_space(3)))

constexpr int N = 4096;
constexpr int D = 1024;            // elements per row == bytes per i8 row
constexpr float QSCALE = 127.0f;
constexpr float LSCALE = 20.0f / (127.0f * 127.0f);  // acc -> logit
constexpr float CBIAS = 21.0f;     // >= max possible logit (20*1 + 1)

typedef int i32x4 __attribute__((ext_vector_type(4)));

// 3072 blocks x 256. One row per wave, 4 coalesced passes (1KB/inst loads,
// 256B/inst stores). Blocks 0..15 zero rowsum; block 16 zeroes the gemm
// done-counter.
__global__ __launch_bounds__(256) void normalize_kernel(
    const float* __restrict__ in0, const float* __restrict__ in1,
    const float* __restrict__ in2, unsigned char* __restrict__ Abuf,
    unsigned char* __restrict__ Bbuf, float* __restrict__ rowsum,
    unsigned int* __restrict__ ctr) {
    const int t = threadIdx.x, lane = t & 63, wave = t >> 6;
    if (blockIdx.x < 16) rowsum[blockIdx.x * 256 + t] = 0.f;
    if (blockIdx.x == 16 && t == 0) *ctr = 0u;
    const int row = blockIdx.x * 4 + wave;  // 0..12287
    const int mat = row >> 12, r = row & (N - 1);
    const float* src = (mat == 0) ? in0 : (mat == 1) ? in1 : in2;
    unsigned char* dst = (mat == 0) ? (Abuf + (size_t)r * D)
                       : (mat == 1) ? (Bbuf + (size_t)r * D)
                                    : (Bbuf + (size_t)(r + N) * D);
    const float4* s4 = (const float4*)(src + (size_t)r * D);
    float4 v[4];
    float p = 0.f;
#pragma unroll
    for (int j = 0; j < 4; ++j) {
        v[j] = s4[lane + 64 * j];  // coalesced: 64 consecutive float4/inst
        p += v[j].x * v[j].x + v[j].y * v[j].y + v[j].z * v[j].z + v[j].w * v[j].w;
    }
#pragma unroll
    for (int m = 1; m < 64; m <<= 1) p += __shfl_xor(p, m);
    const float s = QSCALE / fmaxf(sqrtf(p), 1e-8f);
    unsigned int* d32 = (unsigned int*)dst;
#pragma unroll
    for (int j = 0; j < 4; ++j) {
        int q0 = min(127, max(-127, __float2int_rn(v[j].x * s)));
        int q1 = min(127, max(-127, __float2int_rn(v[j].y * s)));
        int q2 = min(127, max(-127, __float2int_rn(v[j].z * s)));
        int q3 = min(127, max(-127, __float2int_rn(v[j].w * s)));
        d32[lane + 64 * j] = (q0 & 255) | ((q1 & 255) << 8) | ((q2 & 255) << 16)
                           | ((unsigned)(q3 & 255) << 24);
    }
}

// 128x128 tile, BK=128 i8-bytes, 4 waves 2x2, wave 64x64 via 4x4 of
// 16x16x64 i8 MFMA, 2 K-substeps (h) per staged tile, b128 frag reads.
// A:[N,D] i8, B:[2N,D] i8, row-major. C/D: col = lane&15,
// row = (lane>>4)*4 + reg (m89-verified).
// __launch_bounds__(256,4): 4 blocks/CU for inter-block MFMA/stage overlap
// (R13's proven lever). Fused finalize: last-done block reduces rowsum.
__global__ __launch_bounds__(256, 4) void gemm_lse_kernel(
    const unsigned char* __restrict__ A, const unsigned char* __restrict__ B,
    float* __restrict__ rowsum, float* __restrict__ posdiag,
    unsigned int* __restrict__ ctr, float* __restrict__ out) {
    __shared__ __align__(16) char As[128 * 128];  // 16 KiB
    __shared__ __align__(16) char Bs[128 * 128];  // 16 KiB

    const int tid = threadIdx.x;
    const int lane = tid & 63;
    const int wave = tid >> 6;
    const int wr = wave >> 1, wc = wave & 1;
    const int quad = lane >> 4, colid = lane & 15;

    // 2D XCD partition (grid 64x32, flat%8 = XCD round-robin assumed):
    // XCD x owns a 16x16-tile region: rows [16*(x>>2), +16), cols
    // [16*(x&3), +16) -> working set A 2MB + B 2MB (~3MB concurrent) fits
    // the 4MB per-XCD L2 (R13's 1D variant was 4.5MB -> FETCH 39MB thrash).
    const int flat = blockIdx.y * 64 + blockIdx.x;
    const int xcd = flat & 7, tt = flat >> 3;  // tt = 0..255 within XCD
    const int rowBase = (((xcd >> 2) << 4) + (tt & 15)) * 128;
    const int colBase = (((xcd & 3) << 4) + (tt >> 4)) * 128;

    i32x4 acc[4][4];
#pragma unroll
    for (int i = 0; i < 4; ++i)
#pragma unroll
        for (int j = 0; j < 4; ++j) acc[i][j] = {0, 0, 0, 0};

    // Staging (R8-proven, 0 conflicts): thread t fills 16B phys-chunks
    // t+256j; phys chunk c -> row c>>3, phys col c&7; logical col =
    // (c&7)^(row&7); row&7 == (t>>3)&7 for all j.
    const int srow = tid >> 3;                      // 0..31
    const int scol = (tid & 7) ^ ((tid >> 3) & 7);  // 16B units
    const unsigned char* gAb = A + (size_t)(rowBase + srow) * D + scol * 16;
    const unsigned char* gBb = B + (size_t)(colBase + srow) * D + scol * 16;

    // Frag offsets (register-dieted): chunk for K-half h = (h*4+quad) ^
    // (colid&7); rt/ct stride 2048 folded into the read offset immediate.
    const int c0 = (quad ^ (colid & 7)) * 16;
    const int c1 = ((4 + quad) ^ (colid & 7)) * 16;
    const int arow = (wr * 64 + colid) * 128;
    const int brow = (wc * 64 + colid) * 128;
    const int aoff0 = arow + c0, aoff1 = arow + c1;
    const int boff0 = brow + c0, boff1 = brow + c1;

    for (int kb = 0; kb < D / 128; ++kb) {
        const int k0 = kb * 128;
        __syncthreads();  // prior reads done before overwrite
        const unsigned char* gA = gAb + k0;  // rows srow+32j at +32768j
        const unsigned char* gB = gBb + k0;
#pragma unroll
        for (int j = 0; j < 4; ++j) {
            __builtin_amdgcn_global_load_lds((const AS1 void*)(gA + 32768 * j),
                (AS3 void*)(As + (tid + 256 * j) * 16), 16, 0, 0);
            __builtin_amdgcn_global_load_lds((const AS1 void*)(gB + 32768 * j),
                (AS3 void*)(Bs + (tid + 256 * j) * 16), 16, 0, 0);
        }
        __syncthreads();  // staged data visible

#pragma unroll
        for (int h = 0; h < 2; ++h) {
            const int ao = h ? aoff1 : aoff0;
            const int bo = h ? boff1 : boff0;
            i32x4 a[4], b[4];
#pragma unroll
            for (int rt = 0; rt < 4; ++rt)
                a[rt] = *(const i32x4*)(As + ao + rt * 2048);
#pragma unroll
            for (int ct = 0; ct < 4; ++ct)
                b[ct] = *(const i32x4*)(Bs + bo + ct * 2048);
#pragma unroll
            for (int rt = 0; rt < 4; ++rt)
#pragma unroll
                for (int ct = 0; ct < 4; ++ct)
                    acc[rt][ct] = __builtin_amdgcn_mfma_i32_16x16x64_i8(
                        a[rt], b[ct], acc[rt][ct], 0, 0, 0);
        }
    }

    // Epilogue: C map col = lane&15, row = quad*4 + reg.
#pragma unroll
    for (int rt = 0; rt < 4; ++rt) {
        float rsum[4] = {0.f, 0.f, 0.f, 0.f};
#pragma unroll
        for (int ct = 0; ct < 4; ++ct) {
#pragma unroll
            for (int reg = 0; reg < 4; ++reg) {
                const int grow = rowBase + wr * 64 + rt * 16 + quad * 4 + reg;
                const int gcol = colBase + wc * 64 + ct * 16 + colid;
                float logit = (float)acc[rt][ct][reg] * LSCALE;
                if (gcol == grow + N) logit += 1.0f;      // hard-negative weight
                if (gcol == grow) posdiag[grow] = logit;  // unique writer
                rsum[reg] += __expf(logit - CBIAS);
            }
        }
#pragma unroll
        for (int reg = 0; reg < 4; ++reg) {
            float v = rsum[reg];
            v += __shfl_xor(v, 1);
            v += __shfl_xor(v, 2);
            v += __shfl_xor(v, 4);
            v += __shfl_xor(v, 8);
            if (colid == 0) {
                const int grow = rowBase + wr * 64 + rt * 16 + quad * 4 + reg;
                atomicAdd(&rowsum[grow], v);
            }
        }
    }

    // Fused finalize: release this block's writes, count done; last block
    // (acquire via atomic RMW order + fence) reduces all 4096 rows.
    __threadfence();
    __shared__ unsigned int amLast;
    if (tid == 0) amLast = (atomicAdd(ctr, 1u) == 2047u) ? 1u : 0u;
    __syncthreads();
    if (amLast) {
        __threadfence();
        float s = 0.f;
        for (int i = tid; i < N; i += 256)
            s += CBIAS + logf(rowsum[i]) - posdiag[i];
#pragma unroll
        for (int m = 32; m; m >>= 1) s += __shfl_down(s, m);
        __shared__ float red[4];
        if (lane == 0) red[wave] = s;
        __syncthreads();
        if (tid == 0)
            out[0] = (red[0] + red[1] + red[2] + red[3]) / (float)N;
    }
}

extern "C" void kernel_launch(void* const* d_in, const int* in_sizes, int n_in,
                              void* d_out, int out_size, void* d_ws, size_t ws_size,
                              hipStream_t stream) {
    const float* in0 = (const float*)d_in[0];  // input   [N, D] fp32
    const float* in1 = (const float*)d_in[1];  // target  [N, D] fp32
    const float* in2 = (const float*)d_in[2];  // hardneg [N, D] fp32

    // Workspace: Abuf N*D i8 | Bbuf 2N*D i8 | rowsum[N] | posdiag[N] | ctr
    unsigned char* Abuf = (unsigned char*)d_ws;
    unsigned char* Bbuf = Abuf + (size_t)N * D;
    float* rowsum = (float*)(Bbuf + (size_t)2 * N * D);
    float* posdiag = rowsum + N;
    unsigned int* ctr = (unsigned int*)(posdiag + N);

    normalize_kernel<<<3 * N / 4, 256, 0, stream>>>(in0, in1, in2, Abuf, Bbuf,
                                                    rowsum, ctr);
    gemm_lse_kernel<<<dim3(2 * N / 128, N / 128), 256, 0, stream>>>(
        Abuf, Bbuf, rowsum, posdiag, ctr, (float*)d_out);
}

// Round 7
// 128.391 us; speedup vs baseline: 1.9128x; 1.9128x over previous
//
#include <hip/hip_runtime.h>
#include <hip/hip_bf16.h>

// ContrastiveLoss: loss = mean_i [ logsumexp_j(logits[i,:]) - pos_sim[i,i] ]
// logits = [20*xn@tn^T | 20*xn@hn^T + I], rows normalized.
// Round 15: R13 (130.2us champion: 4 blocks/CU TLP, gemm 44.4us) verbatim,
// plus ONE delta: the 2D XCD partition from R14 (proven FETCH 39->16.5MB).
// R14's fused finalize is REVERTED: its per-block __threadfence() (device
// fence = L2 writeback/inv + full drain on non-coherent-L2 gfx950) was the
// 166us regression; the partition itself improved every memory counter.
//  - R8-R12 lesson: intra-block schedules (dbuf/counted-vmcnt/fine phases)
//    are NULL at 1-2 blocks/CU; inter-block TLP is the lever (m114).
//  - Proven pieces untouched: 0-conflict XOR-swizzled 16B-chunk staging,
//    i8 16x16x64 MFMA frag math, epilogue map, register diet (64V+64A),
//    launch_bounds(256,4).
//  - scaled-MFMA banned (R2/R4); b64 LDS reads banned (R5); setprio off
//    (m190); device-scope fences in hot path banned (R14).
//  - logit = acc * (20/127^2); diag cancellation keeps i8 loss error ~1e-3.

#define AS1 __attribute__((address_space(1)))
#define AS3 __attribute__((address_space(3)))

constexpr int N = 4096;
constexpr int D = 1024;            // elements per row == bytes per i8 row
constexpr float QSCALE = 127.0f;
constexpr float LSCALE = 20.0f / (127.0f * 127.0f);  // acc -> logit
constexpr float CBIAS = 21.0f;     // >= max possible logit (20*1 + 1)

typedef int i32x4 __attribute__((ext_vector_type(4)));

// 3072 blocks x 256. One row per wave, 4 coalesced passes: pass j, lane L
// loads float4 #(L+64j) (1KB/inst contiguous) and stores the 4 quantized
// bytes as u32 #(L+64j) (256B/inst contiguous).
// Blocks 0..15 zero rowsum; block 0 zeroes out[0] for finalize's atomics.
__global__ __launch_bounds__(256) void normalize_kernel(
    const float* __restrict__ in0, const float* __restrict__ in1,
    const float* __restrict__ in2, unsigned char* __restrict__ Abuf,
    unsigned char* __restrict__ Bbuf, float* __restrict__ rowsum,
    float* __restrict__ outp) {
    const int t = threadIdx.x, lane = t & 63, wave = t >> 6;
    if (blockIdx.x < 16) rowsum[blockIdx.x * 256 + t] = 0.f;
    if (blockIdx.x == 0 && t == 0) outp[0] = 0.f;
    const int row = blockIdx.x * 4 + wave;  // 0..12287
    const int mat = row >> 12, r = row & (N - 1);
    const float* src = (mat == 0) ? in0 : (mat == 1) ? in1 : in2;
    unsigned char* dst = (mat == 0) ? (Abuf + (size_t)r * D)
                       : (mat == 1) ? (Bbuf + (size_t)r * D)
                                    : (Bbuf + (size_t)(r + N) * D);
    const float4* s4 = (const float4*)(src + (size_t)r * D);
    float4 v[4];
    float p = 0.f;
#pragma unroll
    for (int j = 0; j < 4; ++j) {
        v[j] = s4[lane + 64 * j];  // coalesced: 64 consecutive float4/inst
        p += v[j].x * v[j].x + v[j].y * v[j].y + v[j].z * v[j].z + v[j].w * v[j].w;
    }
#pragma unroll
    for (int m = 1; m < 64; m <<= 1) p += __shfl_xor(p, m);
    const float s = QSCALE / fmaxf(sqrtf(p), 1e-8f);
    unsigned int* d32 = (unsigned int*)dst;
#pragma unroll
    for (int j = 0; j < 4; ++j) {
        int q0 = min(127, max(-127, __float2int_rn(v[j].x * s)));
        int q1 = min(127, max(-127, __float2int_rn(v[j].y * s)));
        int q2 = min(127, max(-127, __float2int_rn(v[j].z * s)));
        int q3 = min(127, max(-127, __float2int_rn(v[j].w * s)));
        d32[lane + 64 * j] = (q0 & 255) | ((q1 & 255) << 8) | ((q2 & 255) << 16)
                           | ((unsigned)(q3 & 255) << 24);
    }
}

// 128x128 tile, BK=128 i8-bytes, 4 waves 2x2, wave 64x64 via 4x4 of
// 16x16x64 i8 MFMA, 2 K-substeps (h) per staged tile, b128 frag reads.
// A:[N,D] i8, B:[2N,D] i8, row-major. C/D: col = lane&15,
// row = (lane>>4)*4 + reg (m89-verified).
// __launch_bounds__(256,4): 4 blocks/CU for inter-block MFMA/stage overlap
// (R13's proven lever, matched prediction: 77 -> 44.4us).
__global__ __launch_bounds__(256, 4) void gemm_lse_kernel(
    const unsigned char* __restrict__ A, const unsigned char* __restrict__ B,
    float* __restrict__ rowsum, float* __restrict__ posdiag) {
    __shared__ __align__(16) char As[128 * 128];  // 16 KiB
    __shared__ __align__(16) char Bs[128 * 128];  // 16 KiB

    const int tid = threadIdx.x;
    const int lane = tid & 63;
    const int wave = tid >> 6;
    const int wr = wave >> 1, wc = wave & 1;
    const int quad = lane >> 4, colid = lane & 15;

    // 2D XCD partition (grid 64x32, flat%8 -> XCD round-robin): XCD x owns
    // the 16x16-tile region rows [16*(x>>2),+16) x cols [16*(x&3),+16):
    // working set A 2MB + B 2MB (~3MB concurrent) fits the 4MB per-XCD L2.
    // R14 measured FETCH 39 -> 16.5MB with this mapping (bijective:
    // rowTile = (xcd>>2)*16 + (tt&15), colTile = (xcd&3)*16 + (tt>>4)).
    const int flat = blockIdx.y * 64 + blockIdx.x;
    const int xcd = flat & 7, tt = flat >> 3;  // tt = 0..255 within XCD
    const int rowBase = (((xcd >> 2) << 4) + (tt & 15)) * 128;
    const int colBase = (((xcd & 3) << 4) + (tt >> 4)) * 128;

    i32x4 acc[4][4];
#pragma unroll
    for (int i = 0; i < 4; ++i)
#pragma unroll
        for (int j = 0; j < 4; ++j) acc[i][j] = {0, 0, 0, 0};

    // Staging (R8-proven, 0 conflicts): thread t fills 16B phys-chunks
    // t+256j; phys chunk c -> row c>>3, phys col c&7; logical col =
    // (c&7)^(row&7); row&7 == (t>>3)&7 for all j.
    const int srow = tid >> 3;                      // 0..31
    const int scol = (tid & 7) ^ ((tid >> 3) & 7);  // 16B units
    const unsigned char* gAb = A + (size_t)(rowBase + srow) * D + scol * 16;
    const unsigned char* gBb = B + (size_t)(colBase + srow) * D + scol * 16;

    // Frag offsets (register-dieted): chunk for K-half h = (h*4+quad) ^
    // (colid&7); rt/ct stride 2048 folded into the read offset immediate.
    const int c0 = (quad ^ (colid & 7)) * 16;
    const int c1 = ((4 + quad) ^ (colid & 7)) * 16;
    const int arow = (wr * 64 + colid) * 128;
    const int brow = (wc * 64 + colid) * 128;
    const int aoff0 = arow + c0, aoff1 = arow + c1;
    const int boff0 = brow + c0, boff1 = brow + c1;

    for (int kb = 0; kb < D / 128; ++kb) {
        const int k0 = kb * 128;
        __syncthreads();  // prior reads done before overwrite
        const unsigned char* gA = gAb + k0;  // rows srow+32j at +32768j
        const unsigned char* gB = gBb + k0;
#pragma unroll
        for (int j = 0; j < 4; ++j) {
            __builtin_amdgcn_global_load_lds((const AS1 void*)(gA + 32768 * j),
                (AS3 void*)(As + (tid + 256 * j) * 16), 16, 0, 0);
            __builtin_amdgcn_global_load_lds((const AS1 void*)(gB + 32768 * j),
                (AS3 void*)(Bs + (tid + 256 * j) * 16), 16, 0, 0);
        }
        __syncthreads();  // staged data visible

#pragma unroll
        for (int h = 0; h < 2; ++h) {
            const int ao = h ? aoff1 : aoff0;
            const int bo = h ? boff1 : boff0;
            i32x4 a[4], b[4];
#pragma unroll
            for (int rt = 0; rt < 4; ++rt)
                a[rt] = *(const i32x4*)(As + ao + rt * 2048);
#pragma unroll
            for (int ct = 0; ct < 4; ++ct)
                b[ct] = *(const i32x4*)(Bs + bo + ct * 2048);
#pragma unroll
            for (int rt = 0; rt < 4; ++rt)
#pragma unroll
                for (int ct = 0; ct < 4; ++ct)
                    acc[rt][ct] = __builtin_amdgcn_mfma_i32_16x16x64_i8(
                        a[rt], b[ct], acc[rt][ct], 0, 0, 0);
        }
    }

    // Epilogue: C map col = lane&15, row = quad*4 + reg.
#pragma unroll
    for (int rt = 0; rt < 4; ++rt) {
        float rsum[4] = {0.f, 0.f, 0.f, 0.f};
#pragma unroll
        for (int ct = 0; ct < 4; ++ct) {
#pragma unroll
            for (int reg = 0; reg < 4; ++reg) {
                const int grow = rowBase + wr * 64 + rt * 16 + quad * 4 + reg;
                const int gcol = colBase + wc * 64 + ct * 16 + colid;
                float logit = (float)acc[rt][ct][reg] * LSCALE;
                if (gcol == grow + N) logit += 1.0f;      // hard-negative weight
                if (gcol == grow) posdiag[grow] = logit;  // unique writer
                rsum[reg] += __expf(logit - CBIAS);
            }
        }
#pragma unroll
        for (int reg = 0; reg < 4; ++reg) {
            float v = rsum[reg];
            v += __shfl_xor(v, 1);
            v += __shfl_xor(v, 2);
            v += __shfl_xor(v, 4);
            v += __shfl_xor(v, 8);
            if (colid == 0) {
                const int grow = rowBase + wr * 64 + rt * 16 + quad * 4 + reg;
                atomicAdd(&rowsum[grow], v);
            }
        }
    }
}

// 16 blocks x 256 thr, one row per thread; wave-reduce then one atomic per
// wave into out (out zeroed by normalize earlier in the stream).
__global__ __launch_bounds__(256) void finalize_kernel(
    const float* __restrict__ rowsum, const float* __restrict__ posdiag,
    float* __restrict__ out) {
    const int i = blockIdx.x * 256 + threadIdx.x;
    float s = CBIAS + logf(rowsum[i]) - posdiag[i];
#pragma unroll
    for (int m = 32; m; m >>= 1) s += __shfl_down(s, m);
    if ((threadIdx.x & 63) == 0) atomicAdd(out, s * (1.0f / (float)N));
}

extern "C" void kernel_launch(void* const* d_in, const int* in_sizes, int n_in,
                              void* d_out, int out_size, void* d_ws, size_t ws_size,
                              hipStream_t stream) {
    const float* in0 = (const float*)d_in[0];  // input   [N, D] fp32
    const float* in1 = (const float*)d_in[1];  // target  [N, D] fp32
    const float* in2 = (const float*)d_in[2];  // hardneg [N, D] fp32

    // Workspace: Abuf N*D i8 (4 MiB) | Bbuf 2N*D i8 (8 MiB) | rowsum | posdiag
    unsigned char* Abuf = (unsigned char*)d_ws;
    unsigned char* Bbuf = Abuf + (size_t)N * D;
    float* rowsum = (float*)(Bbuf + (size_t)2 * N * D);
    float* posdiag = rowsum + N;

    normalize_kernel<<<3 * N / 4, 256, 0, stream>>>(in0, in1, in2, Abuf, Bbuf,
                                                    rowsum, (float*)d_out);
    gemm_lse_kernel<<<dim3(2 * N / 128, N / 128), 256, 0, stream>>>(
        Abuf, Bbuf, rowsum, posdiag);
    finalize_kernel<<<16, 256, 0, stream>>>(rowsum, posdiag, (float*)d_out);
}